// Round 1
// baseline (1222.660 us; speedup 1.0000x reference)
//
#include <hip/hip_runtime.h>
#include <math.h>

#define B_ 16
#define D_ 256
#define T_ 1024
#define K_ 8192
#define N_ (B_*T_)          // 16384 rows

// ---------------- ws layout (4-byte words) ----------------
// [0      .. 16383]  idx      (int)
// [16384  .. 24575]  hist     (int, 8192)
// [24576]            lossAcc  (float)            (contiguous with hist for zeroing)
// [24584  .. 32775]  e2       (float, 8192)
// [32776  .. 98311]  candd    (float, 16384*4)
// [98312  ..163847]  candi    (int,   16384*4)
// total 163848 words = 655 KB

__global__ void vq_zero(int* __restrict__ p, int n) {
    int i = blockIdx.x * 256 + threadIdx.x;
    if (i < n) p[i] = 0;
}

// ||emb_k||^2 : one wave per code, 4 codes per block
__global__ void vq_e2(const float* __restrict__ emb, float* __restrict__ e2) {
    const int tid  = threadIdx.x;
    const int lane = tid & 63;
    const int k    = blockIdx.x * 4 + (tid >> 6);
    float4 v = *(const float4*)&emb[k * D_ + lane * 4];
    float s = v.x*v.x + v.y*v.y + v.z*v.z + v.w*v.w;
    #pragma unroll
    for (int off = 32; off >= 1; off >>= 1) s += __shfl_down(s, off, 64);
    if (lane == 0) e2[k] = s;
}

// fused distance-GEMM + argmin.  grid = 512 blocks:
//   blockIdx>>2 = row-tile (128 rows), blockIdx&3 = K-split (2048 codes each)
// block tile 128 rows x 128 codes, 16x16 threads, 8x8 micro-tile.
__global__ __launch_bounds__(256, 2)
void vq_argmin(const float* __restrict__ z_e, const float* __restrict__ emb,
               const float* __restrict__ e2, float* __restrict__ candd,
               int* __restrict__ candi)
{
    __shared__ float xs[128 * 68];   // [row][d-chunk]  stride 68 (pad, 16B-aligned)
    __shared__ float es[128 * 68];   // [code][d-chunk]

    const int tid = threadIdx.x;
    const int tx  = tid & 15;        // code group
    const int ty  = tid >> 4;        // row group
    const int rb  = blockIdx.x >> 2;
    const int ks  = blockIdx.x & 3;
    const int n0  = rb * 128;        // 128 | T_, so one b per tile
    const int b   = n0 >> 10;
    const int t0  = n0 & 1023;
    const int kbase = ks * 2048;

    float bst[8]; int bidx[8];
    #pragma unroll
    for (int i = 0; i < 8; i++) { bst[i] = 3.4e38f; bidx[i] = 0; }

    for (int kc = 0; kc < 16; ++kc) {
        const int k0 = kbase + kc * 128;
        float acc[8][8];
        #pragma unroll
        for (int i = 0; i < 8; i++)
            #pragma unroll
            for (int j = 0; j < 8; j++) acc[i][j] = 0.f;

        for (int dc = 0; dc < 4; ++dc) {
            const int d0 = dc * 64;
            __syncthreads();                       // protect LDS reuse
            // stage x: 128 rows x 64 d.  per wave: dd fixed, tt contiguous (coalesced 256B)
            #pragma unroll
            for (int p = 0; p < 32; p++) {
                int f  = p * 256 + tid;
                int dd = f >> 7;                   // 0..63
                int tt = f & 127;                  // 0..127
                xs[tt * 68 + dd] = z_e[(b * D_ + d0 + dd) * T_ + t0 + tt];
            }
            // stage e: 128 codes x 64 d, float4 (coalesced 256B/row)
            #pragma unroll
            for (int p = 0; p < 8; p++) {
                int f = p * 256 + tid;
                int c = f >> 4;                    // 0..127
                int q = (f & 15) << 2;             // 0..60
                *(float4*)&es[c * 68 + q] =
                    *(const float4*)&emb[(k0 + c) * D_ + d0 + q];
            }
            __syncthreads();
            // 16 b128 LDS reads per 256 FMA -> 2 FLOP/B (balanced vs CU LDS BW)
            #pragma unroll 4
            for (int d = 0; d < 64; d += 4) {
                float4 ev[8];
                #pragma unroll
                for (int j = 0; j < 8; j++)
                    ev[j] = *(const float4*)&es[(tx + 16 * j) * 68 + d];
                #pragma unroll
                for (int i = 0; i < 8; i++) {
                    float4 xv = *(const float4*)&xs[(ty + 16 * i) * 68 + d];
                    #pragma unroll
                    for (int j = 0; j < 8; j++) {
                        acc[i][j] += xv.x * ev[j].x + xv.y * ev[j].y
                                   + xv.z * ev[j].z + xv.w * ev[j].w;
                    }
                }
            }
        }
        // distances + running argmin (strict < keeps first-min; c ascending in j,kc)
        #pragma unroll
        for (int j = 0; j < 8; j++) {
            const int c = k0 + tx + 16 * j;
            const float ev2 = e2[c];
            #pragma unroll
            for (int i = 0; i < 8; i++) {
                float dist = ev2 - 2.f * acc[i][j];
                if (dist < bst[i]) { bst[i] = dist; bidx[i] = c; }
            }
        }
    }
    __syncthreads();
    // cross-tx reduction per row via LDS (reuse xs/es)
    float* rmin = xs;                 // [128][16]
    int*   ridx = (int*)es;
    #pragma unroll
    for (int i = 0; i < 8; i++) {
        rmin[(ty + 16 * i) * 16 + tx] = bst[i];
        ridx[(ty + 16 * i) * 16 + tx] = bidx[i];
    }
    __syncthreads();
    if (tid < 128) {
        const int r = tid;
        float bd = rmin[r * 16]; int bi = ridx[r * 16];
        #pragma unroll
        for (int x = 1; x < 16; x++) {
            float d2 = rmin[r * 16 + x]; int i2 = ridx[r * 16 + x];
            if (d2 < bd || (d2 == bd && i2 < bi)) { bd = d2; bi = i2; }
        }
        candd[(n0 + r) * 4 + ks] = bd;
        candi[(n0 + r) * 4 + ks] = bi;
    }
}

// reduce the 4 K-split candidates per row; build histogram
__global__ void vq_reduce(const float* __restrict__ candd, const int* __restrict__ candi,
                          int* __restrict__ idx, int* __restrict__ hist)
{
    int r = blockIdx.x * 256 + threadIdx.x;
    if (r >= N_) return;
    float bd = candd[r * 4]; int bi = candi[r * 4];
    #pragma unroll
    for (int s = 1; s < 4; s++) {
        float d2 = candd[r * 4 + s]; int i2 = candi[r * 4 + s];
        if (d2 < bd || (d2 == bd && i2 < bi)) { bd = d2; bi = i2; }
    }
    idx[r] = bi;
    atomicAdd(&hist[bi], 1);
}

// gather z_q, write transposed output, accumulate commitment loss
__global__ __launch_bounds__(256)
void vq_gather(const float* __restrict__ z_e, const float* __restrict__ emb,
               const int* __restrict__ idx, float* __restrict__ out,
               float* __restrict__ lossAcc)
{
    __shared__ float es[64 * 259];   // [t][d], stride 259 (odd-ish -> conflict-free reads)
    __shared__ int   codes[64];
    __shared__ float red[4];
    const int tid = threadIdx.x;
    const int bb  = blockIdx.x >> 4;
    const int t0  = (blockIdx.x & 15) << 6;
    if (tid < 64) codes[tid] = idx[bb * T_ + t0 + tid];
    __syncthreads();
    // stage 64 emb rows (coalesced 1KB per row)
    for (int p = 0; p < 64; p++) {
        es[p * 259 + tid] = emb[codes[p] * D_ + tid];
    }
    __syncthreads();
    const int t  = tid & 63;
    const int ds = tid >> 6;
    float ls = 0.f;
    #pragma unroll 4
    for (int jj = 0; jj < 64; jj++) {
        int d = ds * 64 + jj;
        float e = es[t * 259 + d];
        int gi = (bb * D_ + d) * T_ + t0 + t;
        float x = z_e[gi];
        out[gi] = e;                      // coalesced 256B stores per wave
        float df = e - x;
        ls += df * df;
    }
    #pragma unroll
    for (int off = 32; off >= 1; off >>= 1) ls += __shfl_down(ls, off, 64);
    if ((tid & 63) == 0) red[tid >> 6] = ls;
    __syncthreads();
    if (tid == 0) atomicAdd(lossAcc, red[0] + red[1] + red[2] + red[3]);
}

// entropy -> perplexity, scale loss
__global__ void vq_finalize(const int* __restrict__ hist, const float* __restrict__ lossAcc,
                            float* __restrict__ out_scalars)
{
    __shared__ float red[256];
    const int tid = threadIdx.x;
    float s = 0.f;
    for (int k = tid; k < K_; k += 256) {
        float p = (float)hist[k] * (1.0f / (float)N_);
        s += p * logf(p + 1e-10f);
    }
    red[tid] = s;
    __syncthreads();
    for (int off = 128; off >= 1; off >>= 1) {
        if (tid < off) red[tid] += red[tid + off];
        __syncthreads();
    }
    if (tid == 0) {
        out_scalars[0] = 0.25f * lossAcc[0] * (1.f / (float)(N_ * D_));  // ALPHA*BETA*mean
        out_scalars[1] = expf(-red[0]);
    }
}

extern "C" void kernel_launch(void* const* d_in, const int* in_sizes, int n_in,
                              void* d_out, int out_size, void* d_ws, size_t ws_size,
                              hipStream_t stream) {
    const float* z_e = (const float*)d_in[0];
    const float* emb = (const float*)d_in[1];
    float* out = (float*)d_out;

    int*   ws      = (int*)d_ws;
    int*   idx     = ws;
    int*   hist    = ws + 16384;
    float* lossAcc = (float*)(ws + 24576);
    float* e2      = (float*)(ws + 24584);
    float* candd   = (float*)(ws + 32776);
    int*   candi   = ws + 98312;

    vq_zero    <<<33,   256, 0, stream>>>(hist, 8193);          // hist + lossAcc
    vq_e2      <<<2048, 256, 0, stream>>>(emb, e2);
    vq_argmin  <<<512,  256, 0, stream>>>(z_e, emb, e2, candd, candi);
    vq_reduce  <<<64,   256, 0, stream>>>(candd, candi, idx, hist);
    vq_gather  <<<256,  256, 0, stream>>>(z_e, emb, idx, out, lossAcc);
    vq_finalize<<<1,    256, 0, stream>>>(hist, lossAcc, out + 4194304);
}